// Round 1
// baseline (269.520 us; speedup 1.0000x reference)
//
#include <hip/hip_runtime.h>
#include <stdint.h>

#define D_MODEL 1024
#define T_SEQ   2048
#define BATCH   2
#define NHEAD   16
#define DK      64

typedef short s16x8 __attribute__((ext_vector_type(8)));
typedef float f32x4 __attribute__((ext_vector_type(4)));

#define MFMA16(a, b, c) __builtin_amdgcn_mfma_f32_16x16x32_bf16((a), (b), (c), 0, 0, 0)

__device__ __forceinline__ unsigned short f2bf(float f) {
    union { float f; unsigned u; } v; v.f = f;
    unsigned r = v.u + 0x7fffu + ((v.u >> 16) & 1u);   // RNE
    return (unsigned short)(r >> 16);
}

// ---------------------------------------------------------------- cast x -> bf16
__global__ __launch_bounds__(256) void cast_x(const float* __restrict__ in,
                                              unsigned short* __restrict__ out, int n8) {
    int i = blockIdx.x * 256 + threadIdx.x;
    if (i >= n8) return;
    const float4* p = reinterpret_cast<const float4*>(in) + (size_t)i * 2;
    float4 a = p[0], b = p[1];
    union { s16x8 v; unsigned short u[8]; } o;
    o.u[0] = f2bf(a.x); o.u[1] = f2bf(a.y); o.u[2] = f2bf(a.z); o.u[3] = f2bf(a.w);
    o.u[4] = f2bf(b.x); o.u[5] = f2bf(b.y); o.u[6] = f2bf(b.z); o.u[7] = f2bf(b.w);
    reinterpret_cast<s16x8*>(out)[i] = o.v;
}

// ------------------------------------------ transpose + cast W [R][C] -> bf16 [C][R]
__global__ __launch_bounds__(256) void transpose_cast(const float* __restrict__ in,
                                                      unsigned short* __restrict__ out,
                                                      int R, int C) {
    __shared__ unsigned short tile[64][66];
    int c0 = blockIdx.x * 64, r0 = blockIdx.y * 64;
    int tid = threadIdx.x;
#pragma unroll
    for (int i = 0; i < 16; ++i) {
        int idx = tid + i * 256;
        int r = idx >> 6, c = idx & 63;
        tile[r][c] = f2bf(in[(size_t)(r0 + r) * C + c0 + c]);
    }
    __syncthreads();
#pragma unroll
    for (int i = 0; i < 16; ++i) {
        int idx = tid + i * 256;
        int cc = idx >> 6, rr = idx & 63;
        out[(size_t)(c0 + cc) * R + r0 + rr] = tile[rr][cc];
    }
}

// -------------------------------------------- V [bh][t][64] -> Vt [bh][64][t]
__global__ __launch_bounds__(256) void transpose_v(const unsigned short* __restrict__ in,
                                                   unsigned short* __restrict__ out) {
    __shared__ unsigned short tile[64][66];
    int t0 = blockIdx.x * 64, bh = blockIdx.y;
    int tid = threadIdx.x;
    const unsigned short* src = in + (size_t)bh * T_SEQ * DK;
    unsigned short* dst = out + (size_t)bh * DK * T_SEQ;
#pragma unroll
    for (int i = 0; i < 16; ++i) {
        int idx = tid + i * 256;
        int tr = idx >> 6, d = idx & 63;
        tile[tr][d] = src[(size_t)(t0 + tr) * DK + d];
    }
    __syncthreads();
#pragma unroll
    for (int i = 0; i < 16; ++i) {
        int idx = tid + i * 256;
        int dd = idx >> 6, tt = idx & 63;
        dst[(size_t)dd * T_SEQ + t0 + tt] = tile[tt][dd];
    }
}

// ---------------------------------------------------------------- GEMM (B^T form)
__device__ __forceinline__ void gload_lds16(const void* g, void* l) {
    __builtin_amdgcn_global_load_lds(
        (const __attribute__((address_space(1))) void*)g,
        (__attribute__((address_space(3))) void*)l, 16, 0, 0);
}

// C[M,N] = A[M,K] * Bt[N,K]^T + bias.  EPI=0: scatter to Q/K/V bf16.  EPI=1: fp32 out.
template <int EPI>
__global__ __launch_bounds__(256) void gemm_bt(
    const unsigned short* __restrict__ A, const unsigned short* __restrict__ Bt,
    int K, int N, const float* __restrict__ bias,
    float* __restrict__ outF,
    unsigned short* __restrict__ Qw, unsigned short* __restrict__ Kw,
    unsigned short* __restrict__ Vw) {
    __shared__ __align__(16) unsigned short lds[2][8192];   // per buf: A 4096 + B 4096 shorts
    const int tid = threadIdx.x;
    const int lane = tid & 63, wid = tid >> 6;
    const int g = lane >> 4, l15 = lane & 15;
    const int wm = wid >> 1, wn = wid & 1;
    const int mTile = blockIdx.y, nTile = blockIdx.x;
    const unsigned short* Ab = A + (size_t)mTile * 128 * K;
    const unsigned short* Bb = Bt + (size_t)nTile * 128 * K;
    const int srow = tid >> 2, schunk = (tid & 3) * 8;
    f32x4 acc[4][4] = {};

    auto stage = [&](int buf, int kt) {
        const unsigned short* ga = Ab + (size_t)srow * K + kt * 32 + schunk;
        const unsigned short* gb = Bb + (size_t)srow * K + kt * 32 + schunk;
        unsigned short* la = &lds[buf][tid * 8];
        unsigned short* lb = &lds[buf][4096 + tid * 8];
        gload_lds16(ga, la);
        gload_lds16(ga + (size_t)64 * K, la + 2048);
        gload_lds16(gb, lb);
        gload_lds16(gb + (size_t)64 * K, lb + 2048);
    };

    stage(0, 0);
    __syncthreads();
    const int nk = K >> 5;
    int buf = 0;
    for (int kt = 0; kt < nk; ++kt) {
        if (kt + 1 < nk) stage(buf ^ 1, kt + 1);
        const unsigned short* la = &lds[buf][0];
        const unsigned short* lb = &lds[buf][4096];
        s16x8 af[4], bfr[4];
#pragma unroll
        for (int m = 0; m < 4; ++m)
            af[m] = *(const s16x8*)&la[(wm * 64 + m * 16 + l15) * 32 + g * 8];
#pragma unroll
        for (int n = 0; n < 4; ++n)
            bfr[n] = *(const s16x8*)&lb[(wn * 64 + n * 16 + l15) * 32 + g * 8];
#pragma unroll
        for (int m = 0; m < 4; ++m)
#pragma unroll
            for (int n = 0; n < 4; ++n)
                acc[m][n] = MFMA16(af[m], bfr[n], acc[m][n]);
        __syncthreads();
        buf ^= 1;
    }

    const int rowBase = mTile * 128 + wm * 64;
    const int colBase = nTile * 128 + wn * 64;
#pragma unroll
    for (int m = 0; m < 4; ++m) {
#pragma unroll
        for (int n = 0; n < 4; ++n) {
            int col = colBase + n * 16 + l15;
            float bv = bias[col];
#pragma unroll
            for (int r = 0; r < 4; ++r) {
                int row = rowBase + m * 16 + 4 * g + r;
                float val = acc[m][n][r] + bv;
                if (EPI == 1) {
                    outF[(size_t)row * N + col] = val;
                } else {
                    int b = row >> 11, t = row & 2047;
                    if (col < 1024) {
                        int h = col >> 6, d = col & 63;
                        Qw[(((size_t)(b * NHEAD + h)) * T_SEQ + t) * DK + d] = f2bf(val * 0.125f);
                    } else if (col < 2048) {
                        int h = (col - 1024) >> 6, d = col & 63;
                        Kw[(((size_t)(b * NHEAD + h)) * T_SEQ + t) * DK + d] = f2bf(val);
                    } else {
                        int h = (col - 2048) >> 6, d = col & 63;
                        Vw[(((size_t)(b * NHEAD + h)) * T_SEQ + t) * DK + d] = f2bf(val);
                    }
                }
            }
        }
    }
}

// ---------------------------------------------------------------- flash attention
// grid (T/128, B*H). 4 waves/block, each wave owns 32 q-rows, KVBLK=64.
__global__ __launch_bounds__(256) void attn_fwd(
    const unsigned short* __restrict__ Q, const unsigned short* __restrict__ Kx,
    const unsigned short* __restrict__ Vt, unsigned short* __restrict__ O) {
    __shared__ __align__(16) unsigned short Pl[4][16][72];   // per-wave P tile, 144B rows
    const int tid = threadIdx.x;
    const int lane = tid & 63, wid = tid >> 6;
    const int g = lane >> 4, l15 = lane & 15;
    const int bh = blockIdx.y;
    const int b = bh >> 4, h = bh & 15;
    const int q0 = blockIdx.x * 128 + wid * 32;
    const unsigned short* Qh = Q + (size_t)bh * T_SEQ * DK;
    const unsigned short* Kh = Kx + (size_t)bh * T_SEQ * DK;
    const unsigned short* Vh = Vt + (size_t)bh * DK * T_SEQ;

    s16x8 qf[2][2];
#pragma unroll
    for (int qt = 0; qt < 2; ++qt)
#pragma unroll
        for (int dc = 0; dc < 2; ++dc)
            qf[qt][dc] = *(const s16x8*)&Qh[(size_t)(q0 + qt * 16 + l15) * DK + dc * 32 + g * 8];

    f32x4 o[2][4] = {};
    float mrun[2][4], lrun[2][4];
#pragma unroll
    for (int qt = 0; qt < 2; ++qt)
#pragma unroll
        for (int r = 0; r < 4; ++r) { mrun[qt][r] = -1e30f; lrun[qt][r] = 0.f; }

    for (int kv0 = 0; kv0 < T_SEQ; kv0 += 64) {
        s16x8 kf[4][2];
#pragma unroll
        for (int kq = 0; kq < 4; ++kq)
#pragma unroll
            for (int dc = 0; dc < 2; ++dc)
                kf[kq][dc] = *(const s16x8*)&Kh[(size_t)(kv0 + kq * 16 + l15) * DK + dc * 32 + g * 8];
        s16x8 vf[4][2];
#pragma unroll
        for (int dc16 = 0; dc16 < 4; ++dc16)
#pragma unroll
            for (int kc = 0; kc < 2; ++kc)
                vf[dc16][kc] = *(const s16x8*)&Vh[(size_t)(dc16 * 16 + l15) * T_SEQ + kv0 + kc * 32 + g * 8];

#pragma unroll
        for (int qt = 0; qt < 2; ++qt) {
            f32x4 s[4];
#pragma unroll
            for (int kq = 0; kq < 4; ++kq) {
                f32x4 z = {};
                z = MFMA16(qf[qt][0], kf[kq][0], z);
                z = MFMA16(qf[qt][1], kf[kq][1], z);
                s[kq] = z;
            }
            // wave-parallel row max (rows live across 16 lanes; this lane owns rows 4g+r)
            float tm[4];
#pragma unroll
            for (int r = 0; r < 4; ++r)
                tm[r] = fmaxf(fmaxf(s[0][r], s[1][r]), fmaxf(s[2][r], s[3][r]));
#pragma unroll
            for (int mask = 1; mask <= 8; mask <<= 1)
#pragma unroll
                for (int r = 0; r < 4; ++r)
                    tm[r] = fmaxf(tm[r], __shfl_xor(tm[r], mask));
            float sf[4];
#pragma unroll
            for (int r = 0; r < 4; ++r) {
                float mn = fmaxf(mrun[qt][r], tm[r]);
                sf[r] = __expf(mrun[qt][r] - mn);
                mrun[qt][r] = mn;
            }
            float p[4][4], ts[4];
#pragma unroll
            for (int r = 0; r < 4; ++r) ts[r] = 0.f;
#pragma unroll
            for (int kq = 0; kq < 4; ++kq)
#pragma unroll
                for (int r = 0; r < 4; ++r) {
                    p[kq][r] = __expf(s[kq][r] - mrun[qt][r]);
                    ts[r] += p[kq][r];
                }
            // local (deferred) sum accumulation: reduce across lanes only at the end
#pragma unroll
            for (int r = 0; r < 4; ++r)
                lrun[qt][r] = lrun[qt][r] * sf[r] + ts[r];
#pragma unroll
            for (int dc16 = 0; dc16 < 4; ++dc16)
#pragma unroll
                for (int r = 0; r < 4; ++r)
                    o[qt][dc16][r] *= sf[r];
            // P -> LDS (bf16), re-read as MFMA A-fragments
#pragma unroll
            for (int kq = 0; kq < 4; ++kq)
#pragma unroll
                for (int r = 0; r < 4; ++r)
                    Pl[wid][4 * g + r][kq * 16 + l15] = f2bf(p[kq][r]);
            s16x8 pf0 = *(const s16x8*)&Pl[wid][l15][g * 8];
            s16x8 pf1 = *(const s16x8*)&Pl[wid][l15][32 + g * 8];
#pragma unroll
            for (int dc16 = 0; dc16 < 4; ++dc16) {
                o[qt][dc16] = MFMA16(pf0, vf[dc16][0], o[qt][dc16]);
                o[qt][dc16] = MFMA16(pf1, vf[dc16][1], o[qt][dc16]);
            }
        }
    }

#pragma unroll
    for (int qt = 0; qt < 2; ++qt) {
        // final cross-lane sum reduce (once, not per tile)
#pragma unroll
        for (int mask = 1; mask <= 8; mask <<= 1)
#pragma unroll
            for (int r = 0; r < 4; ++r)
                lrun[qt][r] += __shfl_xor(lrun[qt][r], mask);
        float inv[4];
#pragma unroll
        for (int r = 0; r < 4; ++r) inv[r] = 1.f / lrun[qt][r];
#pragma unroll
        for (int dc16 = 0; dc16 < 4; ++dc16)
#pragma unroll
            for (int r = 0; r < 4; ++r) {
                int q = q0 + qt * 16 + 4 * g + r;
                O[((size_t)(b * T_SEQ + q)) * D_MODEL + h * DK + dc16 * 16 + l15] =
                    f2bf(o[qt][dc16][r] * inv[r]);
            }
    }
}

// ---------------------------------------------------------------- launch
extern "C" void kernel_launch(void* const* d_in, const int* in_sizes, int n_in,
                              void* d_out, int out_size, void* d_ws, size_t ws_size,
                              hipStream_t stream) {
    const float* x    = (const float*)d_in[0];
    const float* Wqkv = (const float*)d_in[1];
    const float* bqkv = (const float*)d_in[2];
    const float* Wout = (const float*)d_in[3];
    const float* bout = (const float*)d_in[4];
    float* out = (float*)d_out;

    char* ws = (char*)d_ws;
    unsigned short* Xbf    = (unsigned short*)(ws + 0);          //  8 MB
    unsigned short* WqkvT  = (unsigned short*)(ws + 8388608);    //  6 MB
    unsigned short* WoutT  = (unsigned short*)(ws + 14680064);   //  2 MB
    unsigned short* Qw     = (unsigned short*)(ws + 16777216);   //  8 MB
    unsigned short* Kw     = (unsigned short*)(ws + 25165824);   //  8 MB
    unsigned short* Vtmp   = (unsigned short*)(ws + 33554432);   //  8 MB
    unsigned short* Vte    = (unsigned short*)(ws + 41943040);   //  8 MB
    unsigned short* Ows    = (unsigned short*)(ws + 50331648);   //  8 MB (ends 56 MB)

    // 1. cast x
    cast_x<<<2048, 256, 0, stream>>>(x, Xbf, (BATCH * T_SEQ * D_MODEL) / 8);
    // 2. transpose weights
    transpose_cast<<<dim3(48, 16), 256, 0, stream>>>(Wqkv, WqkvT, 1024, 3072);
    transpose_cast<<<dim3(16, 16), 256, 0, stream>>>(Wout, WoutT, 1024, 1024);
    // 3. QKV GEMM -> Q/K/V [b,h,t,d]
    gemm_bt<0><<<dim3(24, 32), 256, 0, stream>>>(Xbf, WqkvT, 1024, 3072, bqkv,
                                                 nullptr, Qw, Kw, Vtmp);
    // 4. V -> V^T [b,h,d,t]
    transpose_v<<<dim3(32, 32), 256, 0, stream>>>(Vtmp, Vte);
    // 5. flash attention -> Ows [b,t,h*dk] bf16
    attn_fwd<<<dim3(16, 32), 256, 0, stream>>>(Qw, Kw, Vte, Ows);
    // 6. out projection -> d_out fp32
    gemm_bt<1><<<dim3(8, 32), 256, 0, stream>>>(Ows, WoutT, 1024, 1024, bout,
                                                out, nullptr, nullptr, nullptr);
}

// Round 2
// 266.147 us; speedup vs baseline: 1.0127x; 1.0127x over previous
//
#include <hip/hip_runtime.h>
#include <stdint.h>

#define D_MODEL 1024
#define T_SEQ   2048
#define BATCH   2
#define NHEAD   16
#define DK      64

typedef short s16x8 __attribute__((ext_vector_type(8)));
typedef float f32x4 __attribute__((ext_vector_type(4)));
typedef float f32x16 __attribute__((ext_vector_type(16)));

#define MFMA16(a, b, c) __builtin_amdgcn_mfma_f32_16x16x32_bf16((a), (b), (c), 0, 0, 0)
#define MFMA32(a, b, c) __builtin_amdgcn_mfma_f32_32x32x16_bf16((a), (b), (c), 0, 0, 0)
#define CROW(r) ((((r) & 3)) + 8 * ((r) >> 2))

__device__ __forceinline__ unsigned short f2bf(float f) {
    union { float f; unsigned u; } v; v.f = f;
    unsigned r = v.u + 0x7fffu + ((v.u >> 16) & 1u);   // RNE
    return (unsigned short)(r >> 16);
}

__device__ __forceinline__ unsigned cvtpk_bf16(float lo, float hi) {
    unsigned r;
    asm("v_cvt_pk_bf16_f32 %0, %1, %2" : "=v"(r) : "v"(lo), "v"(hi));
    return r;
}

__device__ __forceinline__ float bperm_f(int srclane, float v) {
    int iv = __builtin_bit_cast(int, v);
    int r = __builtin_amdgcn_ds_bpermute(srclane << 2, iv);
    return __builtin_bit_cast(float, r);
}

// ---------------------------------------------------------------- cast x -> bf16
__global__ __launch_bounds__(256) void cast_x(const float* __restrict__ in,
                                              unsigned short* __restrict__ out, int n8) {
    int i = blockIdx.x * 256 + threadIdx.x;
    if (i >= n8) return;
    const float4* p = reinterpret_cast<const float4*>(in) + (size_t)i * 2;
    float4 a = p[0], b = p[1];
    union { s16x8 v; unsigned short u[8]; } o;
    o.u[0] = f2bf(a.x); o.u[1] = f2bf(a.y); o.u[2] = f2bf(a.z); o.u[3] = f2bf(a.w);
    o.u[4] = f2bf(b.x); o.u[5] = f2bf(b.y); o.u[6] = f2bf(b.z); o.u[7] = f2bf(b.w);
    reinterpret_cast<s16x8*>(out)[i] = o.v;
}

// ------------------------------------------ transpose + cast W [R][C] -> bf16 [C][R]
__global__ __launch_bounds__(256) void transpose_cast(const float* __restrict__ in,
                                                      unsigned short* __restrict__ out,
                                                      int R, int C) {
    __shared__ unsigned short tile[64][66];
    int c0 = blockIdx.x * 64, r0 = blockIdx.y * 64;
    int tid = threadIdx.x;
#pragma unroll
    for (int i = 0; i < 16; ++i) {
        int idx = tid + i * 256;
        int r = idx >> 6, c = idx & 63;
        tile[r][c] = f2bf(in[(size_t)(r0 + r) * C + c0 + c]);
    }
    __syncthreads();
#pragma unroll
    for (int i = 0; i < 16; ++i) {
        int idx = tid + i * 256;
        int cc = idx >> 6, rr = idx & 63;
        out[(size_t)(c0 + cc) * R + r0 + rr] = tile[rr][cc];
    }
}

// -------------------------------------------- V [bh][t][64] -> Vt [bh][64][t]
__global__ __launch_bounds__(256) void transpose_v(const unsigned short* __restrict__ in,
                                                   unsigned short* __restrict__ out) {
    __shared__ unsigned short tile[64][66];
    int t0 = blockIdx.x * 64, bh = blockIdx.y;
    int tid = threadIdx.x;
    const unsigned short* src = in + (size_t)bh * T_SEQ * DK;
    unsigned short* dst = out + (size_t)bh * DK * T_SEQ;
#pragma unroll
    for (int i = 0; i < 16; ++i) {
        int idx = tid + i * 256;
        int tr = idx >> 6, d = idx & 63;
        tile[tr][d] = src[(size_t)(t0 + tr) * DK + d];
    }
    __syncthreads();
#pragma unroll
    for (int i = 0; i < 16; ++i) {
        int idx = tid + i * 256;
        int dd = idx >> 6, tt = idx & 63;
        dst[(size_t)dd * T_SEQ + t0 + tt] = tile[tt][dd];
    }
}

// ---------------------------------------------------------------- GEMM (B^T form)
__device__ __forceinline__ void gload_lds16(const void* g, void* l) {
    __builtin_amdgcn_global_load_lds(
        (const __attribute__((address_space(1))) void*)g,
        (__attribute__((address_space(3))) void*)l, 16, 0, 0);
}

// C[M,N] = A[M,K] * Bt[N,K]^T + bias.  EPI=0: scatter to Q/K/V bf16.  EPI=1: fp32 out.
template <int EPI>
__global__ __launch_bounds__(256) void gemm_bt(
    const unsigned short* __restrict__ A, const unsigned short* __restrict__ Bt,
    int K, int N, const float* __restrict__ bias,
    float* __restrict__ outF,
    unsigned short* __restrict__ Qw, unsigned short* __restrict__ Kw,
    unsigned short* __restrict__ Vw) {
    __shared__ __align__(16) unsigned short lds[2][8192];   // per buf: A 4096 + B 4096 shorts
    const int tid = threadIdx.x;
    const int lane = tid & 63, wid = tid >> 6;
    const int g = lane >> 4, l15 = lane & 15;
    const int wm = wid >> 1, wn = wid & 1;
    const int mTile = blockIdx.y, nTile = blockIdx.x;
    const unsigned short* Ab = A + (size_t)mTile * 128 * K;
    const unsigned short* Bb = Bt + (size_t)nTile * 128 * K;
    const int srow = tid >> 2, schunk = (tid & 3) * 8;
    f32x4 acc[4][4] = {};

    auto stage = [&](int buf, int kt) {
        const unsigned short* ga = Ab + (size_t)srow * K + kt * 32 + schunk;
        const unsigned short* gb = Bb + (size_t)srow * K + kt * 32 + schunk;
        unsigned short* la = &lds[buf][tid * 8];
        unsigned short* lb = &lds[buf][4096 + tid * 8];
        gload_lds16(ga, la);
        gload_lds16(ga + (size_t)64 * K, la + 2048);
        gload_lds16(gb, lb);
        gload_lds16(gb + (size_t)64 * K, lb + 2048);
    };

    stage(0, 0);
    __syncthreads();
    const int nk = K >> 5;
    int buf = 0;
    for (int kt = 0; kt < nk; ++kt) {
        if (kt + 1 < nk) stage(buf ^ 1, kt + 1);
        const unsigned short* la = &lds[buf][0];
        const unsigned short* lb = &lds[buf][4096];
        s16x8 af[4], bfr[4];
#pragma unroll
        for (int m = 0; m < 4; ++m)
            af[m] = *(const s16x8*)&la[(wm * 64 + m * 16 + l15) * 32 + g * 8];
#pragma unroll
        for (int n = 0; n < 4; ++n)
            bfr[n] = *(const s16x8*)&lb[(wn * 64 + n * 16 + l15) * 32 + g * 8];
#pragma unroll
        for (int m = 0; m < 4; ++m)
#pragma unroll
            for (int n = 0; n < 4; ++n)
                acc[m][n] = MFMA16(af[m], bfr[n], acc[m][n]);
        __syncthreads();
        buf ^= 1;
    }

    const int rowBase = mTile * 128 + wm * 64;
    const int colBase = nTile * 128 + wn * 64;
#pragma unroll
    for (int m = 0; m < 4; ++m) {
#pragma unroll
        for (int n = 0; n < 4; ++n) {
            int col = colBase + n * 16 + l15;
            float bv = bias[col];
#pragma unroll
            for (int r = 0; r < 4; ++r) {
                int row = rowBase + m * 16 + 4 * g + r;
                float val = acc[m][n][r] + bv;
                if (EPI == 1) {
                    outF[(size_t)row * N + col] = val;
                } else {
                    int b = row >> 11, t = row & 2047;
                    if (col < 1024) {
                        int h = col >> 6, d = col & 63;
                        Qw[(((size_t)(b * NHEAD + h)) * T_SEQ + t) * DK + d] = f2bf(val * 0.125f);
                    } else if (col < 2048) {
                        int h = (col - 1024) >> 6, d = col & 63;
                        Kw[(((size_t)(b * NHEAD + h)) * T_SEQ + t) * DK + d] = f2bf(val);
                    } else {
                        int h = (col - 2048) >> 6, d = col & 63;
                        Vw[(((size_t)(b * NHEAD + h)) * T_SEQ + t) * DK + d] = f2bf(val);
                    }
                }
            }
        }
    }
}

// ---------------------------------------------------------------- flash attention
// grid (T/128, B*H). 4 waves/block, each wave owns 32 q-rows, KVBLK=64.
// Swapped QK^T (S^T = K·Q^T via 32x32x16 MFMA): lane holds P half-row for
// q = lane&31, k = kt*32 + CROW(r) + 4*hi. In-register softmax, T12 cvt_pk +
// permlane32_swap to build PV A-fragment, T13 defer-max. No LDS.
__global__ __launch_bounds__(256) void attn_fwd(
    const unsigned short* __restrict__ Q, const unsigned short* __restrict__ Kx,
    const unsigned short* __restrict__ Vt, unsigned short* __restrict__ O) {
    const int tid = threadIdx.x;
    const int lane = tid & 63, wid = tid >> 6;
    const int l31 = lane & 31, hi = lane >> 5;
    const int bh = blockIdx.y;
    const int b = bh >> 4, h = bh & 15;
    const int q0 = blockIdx.x * 128 + wid * 32;
    const unsigned short* Qh = Q + (size_t)bh * T_SEQ * DK;
    const unsigned short* Kh = Kx + (size_t)bh * T_SEQ * DK;
    const unsigned short* Vh = Vt + (size_t)bh * DK * T_SEQ;

    // Q fragments: row q = q0+l31, k-chunk = dt*16 + hi*8
    s16x8 qf[4];
#pragma unroll
    for (int dt = 0; dt < 4; ++dt)
        qf[dt] = *(const s16x8*)&Qh[(size_t)(q0 + l31) * DK + dt * 16 + hi * 8];

    f32x16 o0 = {}, o1 = {};
    float m = -1e30f, lr = 0.f;

    for (int kv0 = 0; kv0 < T_SEQ; kv0 += 64) {
        // K fragments: row k = kv0 + kt*32 + l31
        s16x8 kf[2][4];
#pragma unroll
        for (int kt = 0; kt < 2; ++kt)
#pragma unroll
            for (int dt = 0; dt < 4; ++dt)
                kf[kt][dt] = *(const s16x8*)&Kh[(size_t)(kv0 + kt * 32 + l31) * DK + dt * 16 + hi * 8];
        // V fragments (B operand): row d = dt2*32 + l31, k = kv0 + ks*16 + hi*8
        s16x8 vf[2][4];
#pragma unroll
        for (int dt2 = 0; dt2 < 2; ++dt2)
#pragma unroll
            for (int ks = 0; ks < 4; ++ks)
                vf[dt2][ks] = *(const s16x8*)&Vh[(size_t)(dt2 * 32 + l31) * T_SEQ + kv0 + ks * 16 + hi * 8];

        // S^T = K · Q^T : p[kt][r] = S[q=l31][k = kv0 + kt*32 + CROW(r)+4*hi]
        f32x16 p[2] = {};
#pragma unroll
        for (int kt = 0; kt < 2; ++kt)
#pragma unroll
            for (int dt = 0; dt < 4; ++dt)
                p[kt] = MFMA32(kf[kt][dt], qf[dt], p[kt]);

        // in-lane tile max over 32 values + one pair-combine
        float tm = p[0][0];
#pragma unroll
        for (int r = 1; r < 16; ++r) tm = fmaxf(tm, p[0][r]);
#pragma unroll
        for (int r = 0; r < 16; ++r) tm = fmaxf(tm, p[1][r]);
        tm = fmaxf(tm, __shfl_xor(tm, 32));

        // T13 defer-max: only rescale when the max grew past THR
        if (!__all(tm <= m + 8.0f)) {
            float mn = fmaxf(m, tm);
            float sf = __expf(m - mn);
            lr *= sf;
            m = mn;
            float sfr;
#pragma unroll
            for (int r = 0; r < 16; ++r) {
                sfr = bperm_f(CROW(r) + 4 * hi, sf);
                o0[r] *= sfr; o1[r] *= sfr;
            }
        }

        // p = exp(s - m), in-place; accumulate row-sum (own half)
        float ts = 0.f;
#pragma unroll
        for (int kt = 0; kt < 2; ++kt)
#pragma unroll
            for (int r = 0; r < 16; ++r) {
                float e = __expf(p[kt][r] - m);
                p[kt][r] = e;
                ts += e;
            }
        lr += ts;

        // build PV A-fragments in-register (T12) and accumulate O
#pragma unroll
        for (int ks = 0; ks < 4; ++ks) {
            const int kt = ks >> 1, rb = (ks & 1) * 8;
            unsigned w0 = cvtpk_bf16(p[kt][rb + 0], p[kt][rb + 1]);
            unsigned w2 = cvtpk_bf16(p[kt][rb + 4], p[kt][rb + 5]);
            asm volatile("v_permlane32_swap_b32 %0, %1" : "+v"(w0), "+v"(w2));
            unsigned w1 = cvtpk_bf16(p[kt][rb + 2], p[kt][rb + 3]);
            unsigned w3 = cvtpk_bf16(p[kt][rb + 6], p[kt][rb + 7]);
            asm volatile("v_permlane32_swap_b32 %0, %1" : "+v"(w1), "+v"(w3));
            union { unsigned w[4]; s16x8 v; } pu;
            pu.w[0] = w0; pu.w[1] = w1; pu.w[2] = w2; pu.w[3] = w3;
            o0 = MFMA32(pu.v, vf[0][ks], o0);
            o1 = MFMA32(pu.v, vf[1][ks], o1);
        }
    }

    // final: combine row-sum across the lane pair, redistribute 1/l, store
    lr += __shfl_xor(lr, 32);
    float li = 1.f / lr;
#pragma unroll
    for (int r = 0; r < 16; ++r) {
        float lir = bperm_f(CROW(r) + 4 * hi, li);
        int q = q0 + CROW(r) + 4 * hi;
        size_t base = ((size_t)(b * T_SEQ + q)) * D_MODEL + h * DK;
        O[base + l31]      = f2bf(o0[r] * lir);
        O[base + 32 + l31] = f2bf(o1[r] * lir);
    }
}

// ---------------------------------------------------------------- launch
extern "C" void kernel_launch(void* const* d_in, const int* in_sizes, int n_in,
                              void* d_out, int out_size, void* d_ws, size_t ws_size,
                              hipStream_t stream) {
    const float* x    = (const float*)d_in[0];
    const float* Wqkv = (const float*)d_in[1];
    const float* bqkv = (const float*)d_in[2];
    const float* Wout = (const float*)d_in[3];
    const float* bout = (const float*)d_in[4];
    float* out = (float*)d_out;

    char* ws = (char*)d_ws;
    unsigned short* Xbf    = (unsigned short*)(ws + 0);          //  8 MB
    unsigned short* WqkvT  = (unsigned short*)(ws + 8388608);    //  6 MB
    unsigned short* WoutT  = (unsigned short*)(ws + 14680064);   //  2 MB
    unsigned short* Qw     = (unsigned short*)(ws + 16777216);   //  8 MB
    unsigned short* Kw     = (unsigned short*)(ws + 25165824);   //  8 MB
    unsigned short* Vtmp   = (unsigned short*)(ws + 33554432);   //  8 MB
    unsigned short* Vte    = (unsigned short*)(ws + 41943040);   //  8 MB
    unsigned short* Ows    = (unsigned short*)(ws + 50331648);   //  8 MB (ends 56 MB)

    // 1. cast x
    cast_x<<<2048, 256, 0, stream>>>(x, Xbf, (BATCH * T_SEQ * D_MODEL) / 8);
    // 2. transpose weights
    transpose_cast<<<dim3(48, 16), 256, 0, stream>>>(Wqkv, WqkvT, 1024, 3072);
    transpose_cast<<<dim3(16, 16), 256, 0, stream>>>(Wout, WoutT, 1024, 1024);
    // 3. QKV GEMM -> Q/K/V [b,h,t,d]
    gemm_bt<0><<<dim3(24, 32), 256, 0, stream>>>(Xbf, WqkvT, 1024, 3072, bqkv,
                                                 nullptr, Qw, Kw, Vtmp);
    // 4. V -> V^T [b,h,d,t]
    transpose_v<<<dim3(32, 32), 256, 0, stream>>>(Vtmp, Vte);
    // 5. flash attention -> Ows [b,t,h*dk] bf16
    attn_fwd<<<dim3(16, 32), 256, 0, stream>>>(Qw, Kw, Vte, Ows);
    // 6. out projection -> d_out fp32
    gemm_bt<1><<<dim3(8, 32), 256, 0, stream>>>(Ows, WoutT, 1024, 1024, bout,
                                                out, nullptr, nullptr, nullptr);
}